// Round 1
// baseline (1201.169 us; speedup 1.0000x reference)
//
#include <hip/hip_runtime.h>
#include <hip/hip_bf16.h>

typedef short bf16x8 __attribute__((ext_vector_type(8)));
typedef float f32x4 __attribute__((ext_vector_type(4)));

#define MFMA16(A,B,C) __builtin_amdgcn_mfma_f32_16x16x32_bf16(A,B,C,0,0,0)

__device__ __forceinline__ unsigned short f2bf(float f) {
  unsigned int u = __float_as_uint(f);
  u += 0x7fffu + ((u >> 16) & 1u);        // round-to-nearest-even
  return (unsigned short)(u >> 16);
}

// ---- LDS layout (bytes). All row strides are odd multiples of 16B -> <=2-way bank alias on b128 reads.
#define XWS 264   // x window  [64][264] bf16
#define QKS 40    // q,k per head [64][40] bf16
#define VTS 72    // vT per head [32][72] bf16 (d-major)
#define PS_ 72    // probs per head [64][72] bf16
#define OS_ 136   // per-quad attn-out [64][136] bf16
#define OFF_XW 0
#define OFF_Q  33792
#define OFF_K  54272
#define OFF_VT 74752
#define OFF_P  93184
#define OFF_O4 130048
#define LDS_TOTAL 147456

#define NQKV 196608   // 768*256
#define NPROJ 65536   // 256*256

__global__ void convert_w_kernel(const float* __restrict__ qkv_w,
                                 const float* __restrict__ proj_w,
                                 ushort* __restrict__ wsb) {
  int i = blockIdx.x * 256 + threadIdx.x;
  if (i < NQKV) wsb[i] = f2bf(qkv_w[i]);
  else if (i < NQKV + NPROJ) wsb[i] = f2bf(proj_w[i - NQKV]);
}

__global__ __launch_bounds__(512, 2)
void swin_fused_kernel(const float* __restrict__ x,
                       const ushort* __restrict__ qkvw,   // [768][256] bf16
                       const ushort* __restrict__ projw,  // [256][256] bf16
                       const float* __restrict__ proj_b,
                       const float* __restrict__ rel_bias, // [8][64][64] f32
                       float* __restrict__ out) {
  extern __shared__ char smem[];
  ushort* xw  = (ushort*)(smem + OFF_XW);
  ushort* qls = (ushort*)(smem + OFF_Q);
  ushort* kls = (ushort*)(smem + OFF_K);
  ushort* vts = (ushort*)(smem + OFF_VT);
  ushort* pls = (ushort*)(smem + OFF_P);
  ushort* o4s = (ushort*)(smem + OFF_O4);

  const int wid = blockIdx.x;          // window id 0..8191
  const int bb_ = wid >> 10;           // batch
  const int wy  = (wid >> 5) & 31;
  const int wx  = wid & 31;
  const int tid  = threadIdx.x;
  const int wave = tid >> 6;           // 0..7
  const int lane = tid & 63;
  const int l16  = lane & 15;
  const int lq   = lane >> 4;          // 0..3

  // ---- phase 0: stage x window [64 tokens][256 ch] as bf16 (zero-fill padding)
  #pragma unroll
  for (int it = 0; it < 8; ++it) {
    const int t  = it * 8 + wave;
    const int gr = wy * 8 + (t >> 3);
    const int gc = wx * 8 + (t & 7);
    float4 v = make_float4(0.f, 0.f, 0.f, 0.f);
    if (gr < 250 && gc < 250)
      v = *(const float4*)(x + ((size_t)bb_ * 62500 + (size_t)gr * 250 + gc) * 256 + lane * 4);
    ushort4 bv;
    bv.x = f2bf(v.x); bv.y = f2bf(v.y); bv.z = f2bf(v.z); bv.w = f2bf(v.w);
    *(ushort4*)(xw + t * XWS + lane * 4) = bv;
  }

  f32x4 oacc[4][2];                    // persistent proj accumulator: wave owns cols [wave*32, wave*32+32)
  #pragma unroll
  for (int m = 0; m < 4; ++m)
    #pragma unroll
    for (int n = 0; n < 2; ++n)
      oacc[m][n] = f32x4{0.f, 0.f, 0.f, 0.f};

  const int hl = wave >> 1;            // local head 0..3
  const int mh = wave & 1;             // row-half
  const float scale = 0.17677669529663687f;  // 32^-0.5

  for (int quad = 0; quad < 2; ++quad) {
    const int H0 = quad * 4;
    __syncthreads();  // (a) xw ready / previous proj done with o4

    // ---- QKV GEMM: [64,256] x [256, 4heads*96]. 24 n-tiles, wave owns {3w,3w+1,3w+2} (disjoint).
    f32x4 acc[4][3];
    #pragma unroll
    for (int m = 0; m < 4; ++m)
      #pragma unroll
      for (int j = 0; j < 3; ++j)
        acc[m][j] = f32x4{0.f, 0.f, 0.f, 0.f};

    const ushort* bp[3];
    #pragma unroll
    for (int j = 0; j < 3; ++j) {
      const int n = wave * 3 + j;
      const int ty = n >> 3, rem = n & 7;
      const int wrow = ty * 256 + (H0 + (rem >> 1)) * 32 + (rem & 1) * 16 + l16;
      bp[j] = qkvw + (size_t)wrow * 256 + lq * 8;
    }
    #pragma unroll
    for (int kk = 0; kk < 8; ++kk) {
      bf16x8 af[4];
      #pragma unroll
      for (int m = 0; m < 4; ++m)
        af[m] = *(const bf16x8*)(xw + (m * 16 + l16) * XWS + kk * 32 + lq * 8);
      #pragma unroll
      for (int j = 0; j < 3; ++j) {
        bf16x8 bf = *(const bf16x8*)(bp[j] + kk * 32);
        #pragma unroll
        for (int m = 0; m < 4; ++m)
          acc[m][j] = MFMA16(af[m], bf, acc[m][j]);
      }
    }
    // scatter QKV to LDS (q pre-scaled; v transposed)
    #pragma unroll
    for (int j = 0; j < 3; ++j) {
      const int n = wave * 3 + j;
      const int ty = n >> 3, rem = n & 7;
      const int hh = rem >> 1, half = rem & 1;
      const int d = half * 16 + l16;
      #pragma unroll
      for (int m = 0; m < 4; ++m) {
        #pragma unroll
        for (int rr = 0; rr < 4; ++rr) {
          const int tok = m * 16 + lq * 4 + rr;
          const float v = acc[m][j][rr];
          if (ty == 0)      qls[hh * 64 * QKS + tok * QKS + d] = f2bf(v * scale);
          else if (ty == 1) kls[hh * 64 * QKS + tok * QKS + d] = f2bf(v);
          else              vts[hh * 32 * VTS + d * VTS + tok] = f2bf(v);
        }
      }
    }
    __syncthreads();  // (b) q/k/vT ready

    // ---- S = Qs*K^T + bias, softmax (wave owns head hl, rows [mh*32, mh*32+32))
    f32x4 s[2][4];
    {
      bf16x8 qf[2];
      #pragma unroll
      for (int mt = 0; mt < 2; ++mt)
        qf[mt] = *(const bf16x8*)(qls + hl * 64 * QKS + (mh * 32 + mt * 16 + l16) * QKS + lq * 8);
      #pragma unroll
      for (int nt = 0; nt < 4; ++nt) {
        bf16x8 kf = *(const bf16x8*)(kls + hl * 64 * QKS + (nt * 16 + l16) * QKS + lq * 8);
        #pragma unroll
        for (int mt = 0; mt < 2; ++mt)
          s[mt][nt] = MFMA16(qf[mt], kf, (f32x4{0.f, 0.f, 0.f, 0.f}));
      }
    }
    const float* biasb = rel_bias + (size_t)(H0 + hl) * 4096;
    float rcp_[2][4];
    #pragma unroll
    for (int mt = 0; mt < 2; ++mt) {
      #pragma unroll
      for (int rr = 0; rr < 4; ++rr) {
        const int qrow = mh * 32 + mt * 16 + lq * 4 + rr;
        float vmax = -1e30f;
        #pragma unroll
        for (int nt = 0; nt < 4; ++nt) {
          float v = s[mt][nt][rr] + biasb[qrow * 64 + nt * 16 + l16];
          s[mt][nt][rr] = v;
          vmax = fmaxf(vmax, v);
        }
        vmax = fmaxf(vmax, __shfl_xor(vmax, 1));
        vmax = fmaxf(vmax, __shfl_xor(vmax, 2));
        vmax = fmaxf(vmax, __shfl_xor(vmax, 4));
        vmax = fmaxf(vmax, __shfl_xor(vmax, 8));
        float ssum = 0.f;
        #pragma unroll
        for (int nt = 0; nt < 4; ++nt) {
          float e = __expf(s[mt][nt][rr] - vmax);
          ssum += e;
          pls[hl * 64 * PS_ + qrow * PS_ + nt * 16 + l16] = f2bf(e);
        }
        ssum += __shfl_xor(ssum, 1);
        ssum += __shfl_xor(ssum, 2);
        ssum += __shfl_xor(ssum, 4);
        ssum += __shfl_xor(ssum, 8);
        rcp_[mt][rr] = 1.f / ssum;
      }
    }

    // ---- PV: O[32 rows][32 d] per wave (p rows are wave-local; vT cross-wave, covered by (b))
    f32x4 o[2][2];
    #pragma unroll
    for (int mt = 0; mt < 2; ++mt)
      #pragma unroll
      for (int nt = 0; nt < 2; ++nt)
        o[mt][nt] = f32x4{0.f, 0.f, 0.f, 0.f};
    #pragma unroll
    for (int kk = 0; kk < 2; ++kk) {
      bf16x8 pf[2];
      #pragma unroll
      for (int mt = 0; mt < 2; ++mt)
        pf[mt] = *(const bf16x8*)(pls + hl * 64 * PS_ + (mh * 32 + mt * 16 + l16) * PS_ + kk * 32 + lq * 8);
      #pragma unroll
      for (int nt = 0; nt < 2; ++nt) {
        bf16x8 vf = *(const bf16x8*)(vts + hl * 32 * VTS + (nt * 16 + l16) * VTS + kk * 32 + lq * 8);
        #pragma unroll
        for (int mt = 0; mt < 2; ++mt)
          o[mt][nt] = MFMA16(pf[mt], vf, o[mt][nt]);
      }
    }
    #pragma unroll
    for (int mt = 0; mt < 2; ++mt)
      #pragma unroll
      for (int nt = 0; nt < 2; ++nt)
        #pragma unroll
        for (int rr = 0; rr < 4; ++rr) {
          const int tok = mh * 32 + mt * 16 + lq * 4 + rr;
          const int col = hl * 32 + nt * 16 + l16;
          o4s[tok * OS_ + col] = f2bf(o[mt][nt][rr] * rcp_[mt][rr]);
        }
    __syncthreads();  // (c) o4 ready

    // ---- proj partial: oacc += O4[64, quad*128..+128] x projW^T slice
    #pragma unroll
    for (int kk = 0; kk < 4; ++kk) {
      bf16x8 af[4];
      #pragma unroll
      for (int m = 0; m < 4; ++m)
        af[m] = *(const bf16x8*)(o4s + (m * 16 + l16) * OS_ + kk * 32 + lq * 8);
      #pragma unroll
      for (int nt = 0; nt < 2; ++nt) {
        const int c = wave * 32 + nt * 16 + l16;
        bf16x8 bfr = *(const bf16x8*)(projw + (size_t)c * 256 + quad * 128 + kk * 32 + lq * 8);
        #pragma unroll
        for (int m = 0; m < 4; ++m)
          oacc[m][nt] = MFMA16(af[m], bfr, oacc[m][nt]);
      }
    }
  }  // quad

  // ---- epilogue: + proj_b, unpad-scatter to global fp32
  #pragma unroll
  for (int nt = 0; nt < 2; ++nt) {
    const int col = wave * 32 + nt * 16 + l16;
    const float pb = proj_b[col];
    #pragma unroll
    for (int m = 0; m < 4; ++m) {
      #pragma unroll
      for (int rr = 0; rr < 4; ++rr) {
        const int tok = m * 16 + lq * 4 + rr;
        const int gr = wy * 8 + (tok >> 3);
        const int gc = wx * 8 + (tok & 7);
        if (gr < 250 && gc < 250)
          out[((size_t)bb_ * 62500 + (size_t)gr * 250 + gc) * 256 + col] = oacc[m][nt][rr] + pb;
      }
    }
  }
}

extern "C" void kernel_launch(void* const* d_in, const int* in_sizes, int n_in,
                              void* d_out, int out_size, void* d_ws, size_t ws_size,
                              hipStream_t stream) {
  const float* x        = (const float*)d_in[0];
  const float* qkv_w    = (const float*)d_in[1];
  const float* proj_w   = (const float*)d_in[2];
  const float* proj_b   = (const float*)d_in[3];
  const float* rel_bias = (const float*)d_in[4];
  float* out = (float*)d_out;
  ushort* wsb = (ushort*)d_ws;  // [0,196608): qkv_w bf16; [196608, 262144): proj_w bf16

  (void)in_sizes; (void)n_in; (void)out_size; (void)ws_size;

  hipFuncSetAttribute((const void*)swin_fused_kernel,
                      hipFuncAttributeMaxDynamicSharedMemorySize, LDS_TOTAL);

  convert_w_kernel<<<1024, 256, 0, stream>>>(qkv_w, proj_w, wsb);
  swin_fused_kernel<<<8192, 512, LDS_TOTAL, stream>>>(x, wsb, wsb + NQKV, proj_b,
                                                      rel_bias, out);
}